// Round 1
// baseline (968.019 us; speedup 1.0000x reference)
//
#include <hip/hip_runtime.h>

// GraphConstruction: x[1,1024,1024] fp32 -> A[4096,4096] in {0,1} fp32.
// patches[n,r,k] = x[h,w], h = (n&15)*64 + (r>>2)*16 + (n>>8),
//                          w = (r&3)*256 + k*16 + ((n>>4)&15)
// LOCKED NUMERICS (R6..R13, absmax 0):
//   sq[n,k]: acc = p0^2; acc = acc + fl(p_r^2), r ascending (plain adds)
//   G: acc = fmaf(a_r, b_r, acc), r ascending;  d2 = fmaf(-2,G,fl(si+sj))
//   decision: all_k (d2 <= 49.0f)  ==  !any_k (d2 > 49.0f)  (bit-exact,
//   fp max is exact) -> accumulate per-cell FAIL BIT instead of running
//   fp max. A bit-exactly symmetric -> mirror stores.
// R14 = R13 with 128x128 block tile, 8x8 per-thread register tile.
//   R13 was LDS-read-BW bound: 2.0 B per FMA from LDS ~= 5.2 GB ~= 100us
//   at ds_read_b128 rate (85 B/cyc/CU). 8x8 tile halves that to 1.0 B/FMA.
//   R11/R12 lesson (8x4 -> 112-128 VGPR -> occupancy cliff) dodged by
//   replacing m[8][8] (64 VGPR running max) with 2-VGPR fail bitmask:
//   peak live = d(64)+a(32)+b(4)+misc ~= 150 -> 3 waves/SIMD.
//   Swizzle carries over: stride 9 float4 rows, ch = c ^ swzrow(row);
//   row%8 + distinct swz per 8-apart rows -> a/b reads & stage writes are
//   <=2-way (free, m136).

#define NPATCH 4096
#define BT 128
#define NT (NPATCH / BT)   // 32 -> 528 lower-triangle blocks
#define NPH 8
#define KC 2
#define RSTRIDE 9          // float4 per row (8 data chunks + 1 pad)

__device__ __forceinline__ int swzrow(int row) {
    return ((row >> 2) + (row >> 5)) & 7;
}

__global__ __launch_bounds__(256, 3) void adj_kernel(const float* __restrict__ x,
                                                     float* __restrict__ A) {
#pragma clang fp contract(off)
    __shared__ float4 Si[BT * RSTRIDE];
    __shared__ float4 Sj[BT * RSTRIDE];
    __shared__ float sqs[2][KC][BT];

    // linear -> lower-triangle (bi >= bj)
    int t = blockIdx.x;
    int bi = (int)((sqrtf(8.0f * (float)t + 1.0f) - 1.0f) * 0.5f);
    while ((bi + 1) * (bi + 2) / 2 <= t) ++bi;
    while (bi * (bi + 1) / 2 > t) --bi;
    int bj = t - bi * (bi + 1) / 2;

    const int i0 = bi * BT;
    const int j0 = bj * BT;
    const int tid = threadIdx.x;
    const int tx = tid & 15;       // j-cols tx*8..+7
    const int ty = tid >> 4;       // i-rows ty*8..+7

    unsigned fail0 = 0u, fail1 = 0u;   // bit u*8+v (u<4) / (u-4)*8+v

    for (int kp = 0; kp < NPH; ++kp) {
        __syncthreads();
        // ---- stage: 2048 float4 loads, 8/thread; each covers 4 rows ----
#pragma unroll
        for (int l = 0; l < 8; ++l) {
            int gid = l * 256 + tid;
            int side = gid >> 10;
            int q = gid & 1023;            // m4(4) | r(4) | kl(1) | g(1)
            int g = q & 1;
            int kl = (q >> 1) & 1;
            int r = (q >> 2) & 15;
            int m4 = q >> 6;
            int k = kp * KC + kl;
            int bt = side ? bj : bi;
            int h = m4 * 64 + (r >> 2) * 16 + (bt >> 1);
            int w0 = (r & 3) * 256 + k * 16 + 8 * (bt & 1) + 4 * g;
            float4 v = *(const float4*)&x[h * 1024 + w0];
            const float* vp = (const float*)&v;
            int c = (kl << 2) | (r >> 2);
            int e = r & 3;
            float* Sb = side ? (float*)Sj : (float*)Si;
#pragma unroll
            for (int dd = 0; dd < 4; ++dd) {   // elem dd -> row (4g+dd)*16+m4
                int row = (4 * g + dd) * 16 + m4;
                int ch = c ^ swzrow(row);
                Sb[(row * RSTRIDE + ch) * 4 + e] = vp[dd];
            }
        }
        __syncthreads();
        // ---- per-column sq: plain adds, r ascending (2 values/thread) ----
#pragma unroll
        for (int s = 0; s < 2; ++s) {
            int idx = s * 256 + tid;
            int side = idx >> 8;
            int kl = (idx >> 7) & 1;
            int row = idx & 127;
            const float4* Sb = (side ? Sj : Si) + row * RSTRIDE;
            int swz = swzrow(row);
            float acc;
            {
                float4 v = Sb[(kl * 4) ^ swz];
                acc = v.x * v.x;
                float t1 = v.y * v.y; acc = acc + t1;
                float t2 = v.z * v.z; acc = acc + t2;
                float t3 = v.w * v.w; acc = acc + t3;
            }
#pragma unroll
            for (int rc = 1; rc < 4; ++rc) {
                float4 v = Sb[(kl * 4 + rc) ^ swz];
                float t0 = v.x * v.x; acc = acc + t0;
                float t1 = v.y * v.y; acc = acc + t1;
                float t2 = v.z * v.z; acc = acc + t2;
                float t3 = v.w * v.w; acc = acc + t3;
            }
            sqs[side][kl][row] = acc;
        }
        __syncthreads();
        // ---- compute: 8x8 cells, fmaf chains r ascending ----
#pragma unroll
        for (int kl = 0; kl < KC; ++kl) {
            float d[8][8];
#pragma unroll
            for (int u = 0; u < 8; ++u)
#pragma unroll
                for (int v = 0; v < 8; ++v) d[u][v] = 0.0f;
#pragma unroll
            for (int rc = 0; rc < 4; ++rc) {
                int c = kl * 4 + rc;
                float4 a[8];
#pragma unroll
                for (int u = 0; u < 8; ++u) {
                    int row = ty * 8 + u;
                    a[u] = Si[row * RSTRIDE + (c ^ swzrow(row))];
                }
#pragma unroll
                for (int v = 0; v < 8; ++v) {
                    int row = tx * 8 + v;
                    float4 b = Sj[row * RSTRIDE + (c ^ swzrow(row))];
#pragma unroll
                    for (int u = 0; u < 8; ++u) {
                        d[u][v] = fmaf(a[u].x, b.x, d[u][v]);
                        d[u][v] = fmaf(a[u].y, b.y, d[u][v]);
                        d[u][v] = fmaf(a[u].z, b.z, d[u][v]);
                        d[u][v] = fmaf(a[u].w, b.w, d[u][v]);
                    }
                }
            }
            float4 si0 = *(const float4*)&sqs[0][kl][ty * 8];
            float4 si1 = *(const float4*)&sqs[0][kl][ty * 8 + 4];
            float4 sj0 = *(const float4*)&sqs[1][kl][tx * 8];
            float4 sj1 = *(const float4*)&sqs[1][kl][tx * 8 + 4];
            float si[8] = {si0.x, si0.y, si0.z, si0.w, si1.x, si1.y, si1.z, si1.w};
            float sj[8] = {sj0.x, sj0.y, sj0.z, sj0.w, sj1.x, sj1.y, sj1.z, sj1.w};
#pragma unroll
            for (int u = 0; u < 8; ++u)
#pragma unroll
                for (int v = 0; v < 8; ++v) {
                    float s = si[u] + sj[v];              // fl(si+sj)
                    float d2 = fmaf(-2.0f, d[u][v], s);   // fl(s-2G)
                    unsigned bad = (d2 > 49.0f) ? 1u : 0u;
                    if (u < 4) fail0 |= bad << (u * 8 + v);
                    else       fail1 |= bad << ((u - 4) * 8 + v);
                }
        }
    }

    // ---- stores: direct + mirrored (A exactly symmetric) ----
#pragma unroll
    for (int u = 0; u < 8; ++u) {
        unsigned m8 = ((u < 4) ? (fail0 >> (u * 8)) : (fail1 >> ((u - 4) * 8))) & 0xffu;
        float4 o0, o1;
        o0.x = (m8 & 1u)   ? 0.0f : 1.0f;
        o0.y = (m8 & 2u)   ? 0.0f : 1.0f;
        o0.z = (m8 & 4u)   ? 0.0f : 1.0f;
        o0.w = (m8 & 8u)   ? 0.0f : 1.0f;
        o1.x = (m8 & 16u)  ? 0.0f : 1.0f;
        o1.y = (m8 & 32u)  ? 0.0f : 1.0f;
        o1.z = (m8 & 64u)  ? 0.0f : 1.0f;
        o1.w = (m8 & 128u) ? 0.0f : 1.0f;
        size_t base = (size_t)(i0 + ty * 8 + u) * NPATCH + j0 + tx * 8;
        *(float4*)&A[base] = o0;
        *(float4*)&A[base + 4] = o1;
    }
    if (bi != bj) {
#pragma unroll
        for (int v = 0; v < 8; ++v) {
            float4 o0, o1;
            o0.x = ((fail0 >> (0 * 8 + v)) & 1u) ? 0.0f : 1.0f;
            o0.y = ((fail0 >> (1 * 8 + v)) & 1u) ? 0.0f : 1.0f;
            o0.z = ((fail0 >> (2 * 8 + v)) & 1u) ? 0.0f : 1.0f;
            o0.w = ((fail0 >> (3 * 8 + v)) & 1u) ? 0.0f : 1.0f;
            o1.x = ((fail1 >> (0 * 8 + v)) & 1u) ? 0.0f : 1.0f;
            o1.y = ((fail1 >> (1 * 8 + v)) & 1u) ? 0.0f : 1.0f;
            o1.z = ((fail1 >> (2 * 8 + v)) & 1u) ? 0.0f : 1.0f;
            o1.w = ((fail1 >> (3 * 8 + v)) & 1u) ? 0.0f : 1.0f;
            size_t base = (size_t)(j0 + tx * 8 + v) * NPATCH + i0 + ty * 8;
            *(float4*)&A[base] = o0;
            *(float4*)&A[base + 4] = o1;
        }
    }
}

extern "C" void kernel_launch(void* const* d_in, const int* in_sizes, int n_in,
                              void* d_out, int out_size, void* d_ws, size_t ws_size,
                              hipStream_t stream) {
    const float* x = (const float*)d_in[0];
    float* A = (float*)d_out;
    (void)d_ws; (void)ws_size;

    const int nblk = NT * (NT + 1) / 2;  // 528
    adj_kernel<<<nblk, 256, 0, stream>>>(x, A);
}